// Round 3
// baseline (227.078 us; speedup 1.0000x reference)
//
#include <hip/hip_runtime.h>
#include <hip/hip_bf16.h>
#include <math.h>

// Problem constants (fixed by the reference).
constexpr int Ac = 16;    // actions
constexpr int Bc = 32;    // batch
constexpr int Lc = 1024;  // sequence
constexpr int Xc = 1024;  // x feature
constexpr int Yc = 1024;  // y feature
constexpr int Cc = Ac + Bc;  // 48 combined coefficient rows

// ---------------------------------------------------------------------------
// Wave/block reduction helpers (wave = 64 lanes on CDNA)
// ---------------------------------------------------------------------------
__device__ __forceinline__ float waveReduceSum(float v) {
#pragma unroll
    for (int off = 32; off > 0; off >>= 1) v += __shfl_down(v, off, 64);
    return v;
}

__device__ __forceinline__ float waveReduceMax(float v) {
#pragma unroll
    for (int off = 32; off > 0; off >>= 1) v = fmaxf(v, __shfl_down(v, off, 64));
    return v;
}

// ---------------------------------------------------------------------------
// k1: O[48,X] = C[48,Y] @ W[Y,X]; C rows 0..15 = wa_h, rows 16..47 = y.
// O rows 0..15 -> s_raw (pre-softmax scores), rows 16..47 -> yW.
// grid (X/256=4, Y/16=64) = 256 blocks (1/CU). Coef chunk [48x16] in LDS,
// 16 weight values prefetched per thread, 768 FMAs, 48 atomicAdds.
// ---------------------------------------------------------------------------
__global__ __launch_bounds__(256) void k1_proj(
        const float* __restrict__ weight, const float* __restrict__ yv,
        const float* __restrict__ wa_h, float* __restrict__ s_raw,
        float* __restrict__ yW) {
    const int x  = blockIdx.x * 256 + threadIdx.x;
    const int y0 = blockIdx.y * 16;

    __shared__ float cLDS[Cc][16];  // 3 KiB

#pragma unroll
    for (int k = 0; k < 3; ++k) {
        const int idx = threadIdx.x + k * 256;
        const int row = idx >> 4;
        const int col = idx & 15;
        cLDS[row][col] = (row < Ac) ? wa_h[row * Yc + y0 + col]
                                    : yv[(row - Ac) * Yc + y0 + col];
    }

    float w[16];
#pragma unroll
    for (int t = 0; t < 16; ++t) w[t] = weight[(size_t)(y0 + t) * Xc + x];

    __syncthreads();

    float acc[Cc];
#pragma unroll
    for (int j = 0; j < Cc; ++j) acc[j] = 0.0f;

    const float4* cvec = (const float4*)cLDS;
#pragma unroll
    for (int j = 0; j < Cc; ++j) {
#pragma unroll
        for (int q = 0; q < 4; ++q) {
            const float4 c = cvec[j * 4 + q];  // LDS b128 broadcast
            acc[j] = fmaf(w[q * 4 + 0], c.x, acc[j]);
            acc[j] = fmaf(w[q * 4 + 1], c.y, acc[j]);
            acc[j] = fmaf(w[q * 4 + 2], c.z, acc[j]);
            acc[j] = fmaf(w[q * 4 + 3], c.w, acc[j]);
        }
    }

#pragma unroll
    for (int j = 0; j < Ac; ++j) atomicAdd(&s_raw[j * Xc + x], acc[j]);
#pragma unroll
    for (int j = Ac; j < Cc; ++j) atomicAdd(&yW[(j - Ac) * Xc + x], acc[j]);
}

// ---------------------------------------------------------------------------
// k2 (fused): per action a, p = softmax_x(s_raw[a,:]); then for every b with
// actions[b]==a, Wy[b,:] = yW[b,:]*p + bias. grid: A=16 blocks x 256 threads.
// Kills the per-block yW/score2/bias staging k3 used to redo 2048 times.
// ---------------------------------------------------------------------------
__global__ __launch_bounds__(256) void k2_softmax_wy(
        const float* __restrict__ s_raw, const float* __restrict__ yW,
        const float* __restrict__ bias, const int* __restrict__ actions,
        float* __restrict__ Wy) {
    const int a    = blockIdx.x;
    const int tid  = threadIdx.x;
    const int wave = tid >> 6;
    const int lane = tid & 63;
    __shared__ float smax[4];
    __shared__ float ssum[4];

    float v[4];
    float mx = -INFINITY;
#pragma unroll
    for (int k = 0; k < 4; ++k) {
        v[k] = s_raw[a * Xc + tid + k * 256];
        mx = fmaxf(mx, v[k]);
    }
    mx = waveReduceMax(mx);
    if (lane == 0) smax[wave] = mx;
    __syncthreads();
    mx = fmaxf(fmaxf(smax[0], smax[1]), fmaxf(smax[2], smax[3]));

    float sum = 0.0f;
#pragma unroll
    for (int k = 0; k < 4; ++k) {
        v[k] = __expf(v[k] - mx);
        sum += v[k];
    }
    sum = waveReduceSum(sum);
    if (lane == 0) ssum[wave] = sum;
    __syncthreads();
    sum = ssum[0] + ssum[1] + ssum[2] + ssum[3];

    const float inv = 1.0f / sum;
    float p[4], bi[4];
#pragma unroll
    for (int k = 0; k < 4; ++k) {
        p[k]  = v[k] * inv;
        bi[k] = bias[tid + k * 256];
    }

    // actions is wave-uniform -> scalar loads; branch is block-uniform.
    for (int b = 0; b < Bc; ++b) {
        if (actions[b] == a) {
#pragma unroll
            for (int k = 0; k < 4; ++k) {
                const int xi = tid + k * 256;
                Wy[b * Xc + xi] = fmaf(yW[b * Xc + xi], p[k], bi[k]);
            }
        }
    }
}

// ---------------------------------------------------------------------------
// k3: xWy[b,l] = sum_x x[b,l,x] * Wy[b,x]. Streams all 128 MB of x — the
// HBM-bound term (~20.3 us floor at 6.3 TB/s).
// grid: (L/32, B) = 1024 blocks, 4 waves; each wave 8 rows, 2 at a time
// (8 independent float4 loads in flight per iteration).
// ---------------------------------------------------------------------------
__global__ __launch_bounds__(256) void k3_dot(
        const float* __restrict__ x, const float* __restrict__ Wy,
        float* __restrict__ xWy) {
    const int b  = blockIdx.y;
    const int l0 = blockIdx.x * 32;
    __shared__ float WyS[Xc];

    ((float4*)WyS)[threadIdx.x] = ((const float4*)(Wy + (size_t)b * Xc))[threadIdx.x];
    __syncthreads();

    const int wave = threadIdx.x >> 6;
    const int lane = threadIdx.x & 63;
    const float4* WyV = (const float4*)WyS;

#pragma unroll
    for (int i = 0; i < 8; i += 2) {
        const int l = l0 + wave * 8 + i;
        const float4* xp0 = (const float4*)(x + ((size_t)b * Lc + l) * Xc);
        const float4* xp1 = xp0 + (Xc / 4);
        float acc0 = 0.0f, acc1 = 0.0f;
#pragma unroll
        for (int k = 0; k < 4; ++k) {
            const int idx = lane + k * 64;
            const float4 x0 = xp0[idx];
            const float4 x1 = xp1[idx];
            const float4 wv = WyV[idx];
            acc0 = fmaf(x0.x, wv.x, acc0);
            acc0 = fmaf(x0.y, wv.y, acc0);
            acc0 = fmaf(x0.z, wv.z, acc0);
            acc0 = fmaf(x0.w, wv.w, acc0);
            acc1 = fmaf(x1.x, wv.x, acc1);
            acc1 = fmaf(x1.y, wv.y, acc1);
            acc1 = fmaf(x1.z, wv.z, acc1);
            acc1 = fmaf(x1.w, wv.w, acc1);
        }
        acc0 = waveReduceSum(acc0);
        acc1 = waveReduceSum(acc1);
        if (lane == 0) {
            xWy[b * Lc + l]     = acc0;
            xWy[b * Lc + l + 1] = acc1;
        }
    }
}

// ---------------------------------------------------------------------------
// k4: out[b,:] = log_softmax_L(where(mask, -inf, xWy[b,:])). grid: B blocks.
// ---------------------------------------------------------------------------
__global__ __launch_bounds__(256) void k4_logsoftmax(
        const float* __restrict__ xWy, const unsigned char* __restrict__ mask,
        float* __restrict__ out) {
    const int b    = blockIdx.x;
    const int tid  = threadIdx.x;
    const int wave = tid >> 6;
    const int lane = tid & 63;
    __shared__ float smax[4];
    __shared__ float ssum[4];

    float v[4];
    float mx = -INFINITY;
#pragma unroll
    for (int k = 0; k < 4; ++k) {
        const int l = tid + k * 256;
        float t = xWy[b * Lc + l];
        if (mask[b * Lc + l]) t = -INFINITY;
        v[k] = t;
        mx = fmaxf(mx, t);
    }
    mx = waveReduceMax(mx);
    if (lane == 0) smax[wave] = mx;
    __syncthreads();
    mx = fmaxf(fmaxf(smax[0], smax[1]), fmaxf(smax[2], smax[3]));

    float sum = 0.0f;
#pragma unroll
    for (int k = 0; k < 4; ++k) sum += __expf(v[k] - mx);
    sum = waveReduceSum(sum);
    if (lane == 0) ssum[wave] = sum;
    __syncthreads();
    sum = ssum[0] + ssum[1] + ssum[2] + ssum[3];

    const float lse = mx + __logf(sum);
#pragma unroll
    for (int k = 0; k < 4; ++k) out[b * Lc + tid + k * 256] = v[k] - lse;
}

// ---------------------------------------------------------------------------
// Launch. Inputs (setup_inputs order):
//   0 x      [B,L,X] f32      1 y      [B,Y] f32     2 x_mask [B,L] bool
//   3 actions[B] int32        4 weight [Y,X] f32     5 bias   [X] f32
//   6 wa_h   [A,Y,1] f32
// Output: [B,L] f32 log-softmax.
// Workspace layout:
//   [0,64K)      s_raw  A*X f32  (atomic-accumulated, zeroed below)
//   [64K,192K)   yW     B*X f32  (atomic-accumulated, zeroed below)
//   [192K,320K)  Wy     B*X f32  (fully overwritten by k2)
//   [320K,448K)  xWy    B*L f32  (fully overwritten by k3)
// ---------------------------------------------------------------------------
extern "C" void kernel_launch(void* const* d_in, const int* in_sizes, int n_in,
                              void* d_out, int out_size, void* d_ws, size_t ws_size,
                              hipStream_t stream) {
    const float* x          = (const float*)d_in[0];
    const float* yv         = (const float*)d_in[1];
    const unsigned char* xm = (const unsigned char*)d_in[2];
    const int* actions      = (const int*)d_in[3];
    const float* weight     = (const float*)d_in[4];
    const float* bias       = (const float*)d_in[5];
    const float* wa_h       = (const float*)d_in[6];
    float* out              = (float*)d_out;

    char* ws     = (char*)d_ws;
    float* s_raw = (float*)(ws);
    float* yW    = (float*)(ws + 64 * 1024);
    float* Wy    = (float*)(ws + 192 * 1024);
    float* xWy   = (float*)(ws + 320 * 1024);

    // Zero only the atomic accumulation buffers (192 KiB).
    hipMemsetAsync(d_ws, 0, 192 * 1024, stream);

    k1_proj<<<dim3(Xc / 256, Yc / 16), 256, 0, stream>>>(weight, yv, wa_h, s_raw, yW);
    k2_softmax_wy<<<Ac, 256, 0, stream>>>(s_raw, yW, bias, actions, Wy);
    k3_dot<<<dim3(Lc / 32, Bc), 256, 0, stream>>>(x, Wy, xWy);
    k4_logsoftmax<<<Bc, 256, 0, stream>>>(xWy, xm, out);
}